// Round 8
// baseline (86.428 us; speedup 1.0000x reference)
//
#include <hip/hip_runtime.h>

#define Tn 256
// Recurrence carried as u = -(10*log2e) * r  (r = DTW partial cost).
// softmin: u_new = max3(u) + log2(1 + 2^(med-max) + 2^(min-max)) - 14.4269504*cost
// cost = 0.6*om^2*dl1 pre-folded as cost_u = -8.65617024*om^2*dl1 (data-only).
// SYMMETRY: sdtw(x,y) == sdtw(y,x) exactly (transpose DP, softmin symmetric,
// band symmetric) -> reference's sdtw(gt,pred) call is NOT computed; final
// kernel doubles the sdtw(pred,gt) mean.
#define UBIG (-1.442695e9f)   // u-image of BIG=1e8
#define E2(v)  __builtin_amdgcn_exp2f(v)   // native v_exp_f32 (2^x)
#define LG2(v) __builtin_amdgcn_logf(v)    // native v_log_f32 (log2 x)

// Async 4-wave pipeline: wave w owns rows 64w+1..64w+64 (1 row/lane).
// up via DPP wave_shr1 (lane0 <- boundary via the DPP 'old' operand).
// Cross-wave boundary via LDS ring + volatile progress counters.
// Cost math is software-pipelined one chunk ahead (cc/cn double buffer) so
// its ds_reads+trans fill the serial core's stall slots.
// Blocks 384..511 run the (independent) stats pass instead.
__global__ __launch_bounds__(256) void sdtw_kernel(
    const float* __restrict__ pred, const float* __restrict__ gt,
    const float* __restrict__ mu, const float* __restrict__ lv,
    const float* __restrict__ ptc,
    const int* __restrict__ perm_gen, const int* __restrict__ perm_real,
    float* __restrict__ ws) {
  __shared__ float ylds[Tn][3];        // y sequence, AoS
  __shared__ float rng[3][512];        // boundary ring: rng[w][d] = u[64(w+1)][d]
  __shared__ volatile int prog[4];     // producer progress (highest d published)
  __shared__ float red[256];           // stats-path reduction buffer
  __shared__ float gtr_sh;

  const int t = threadIdx.x;

  if (blockIdx.x >= 384) {             // ---------- stats path ----------
    const int b = blockIdx.x - 384;

    // KL: -0.5 * sum_L (1 + lv - mu^2 - exp(lv)), free bits, relu
    float v = 0.0f;
    if (t < 128) {
      const float m = mu[b * 128 + t];
      const float l = lv[b * 128 + t];
      v = 1.0f + l - m * m - __expf(l);
    }
    red[t] = v; __syncthreads();
    for (int s = 128; s > 0; s >>= 1) { if (t < s) red[t] += red[t + s]; __syncthreads(); }
    if (t == 0) ws[512 + b] = fmaxf(-0.5f * red[0] - 0.5f, 0.0f);
    __syncthreads();

    // gt_trans: sum |gt[b,t+1,2] - gt[b,t,2]|
    float g = 0.0f;
    if (t < Tn - 1)
      g = fabsf(gt[(b * Tn + t + 1) * 3 + 2] - gt[(b * Tn + t) * 3 + 2]);
    red[t] = g; __syncthreads();
    for (int s = 128; s > 0; s >>= 1) { if (t < s) red[t] += red[t + s]; __syncthreads(); }
    if (t == 0) gtr_sh = red[0];
    __syncthreads();
    const float gtr = gtr_sh;

    // soft transitions of pred touch channel
    float p = 0.0f;
    if (t < Tn - 1) {
      const float z0 = (pred[(b * Tn + t) * 3 + 2]     - 0.5f) * 10.0f;
      const float z1 = (pred[(b * Tn + t + 1) * 3 + 2] - 0.5f) * 10.0f;
      const float s0 = 1.0f / (1.0f + __expf(-z0));
      const float s1 = 1.0f / (1.0f + __expf(-z1));
      p = fabsf(s1 - s0);
    }
    red[t] = p; __syncthreads();
    for (int s = 128; s > 0; s >>= 1) { if (t < s) red[t] += red[t + s]; __syncthreads(); }
    if (t == 0) {
      const float pts = red[0];
      const float d1 = ptc[b] - gtr;
      ws[640 + b] = d1 * d1;        // aux per-b
      const float d2 = pts - gtr;
      ws[768 + b] = d2 * d2;        // trans_reg per-b
    }
    return;
  }

  // ---------- sdtw path (3 calls: c0=(pred,gt), c1=d_gen, c2=d_real) ----------
  const int blk = blockIdx.x;
  const int c = blk >> 7;        // which of the 3 sdtw calls
  const int b = blk & 127;       // batch element

  const float* x;
  const float* y;
  if (c == 0)      { x = pred + b * Tn * 3; y = gt   + b * Tn * 3; }
  else if (c == 1) { x = pred + b * Tn * 3; y = pred + perm_gen[b]  * Tn * 3; }
  else             { x = gt   + b * Tn * 3; y = gt   + perm_real[b] * Tn * 3; }

  const int w = t >> 6;
  const int lane = t & 63;
  float* rngf = (float*)&rng[0][0];

  // producers feed the pipeline: prioritize upstream waves (literal-arg ladder)
  if (w == 0)      __builtin_amdgcn_s_setprio(3);
  else if (w == 1) __builtin_amdgcn_s_setprio(2);
  else if (w == 2) __builtin_amdgcn_s_setprio(1);

  // stage y, init ring to UBIG, init counters
  for (int k = t; k < Tn * 3; k += 256) (&ylds[0][0])[k] = y[k];
  for (int k = t; k < 3 * 512; k += 256) rngf[k] = UBIG;
  if (t < 4) prog[t] = 0;

  const float x0 = x[t * 3 + 0];
  const float x1 = x[t * 3 + 1];
  const float x2 = x[t * 3 + 2];

  const int i = t + 1;               // matrix row, 1..256
  const int lo = max(i + 1, 2 * i - 150);
  const int hi = min(i + Tn, 2 * i + 150);
  const unsigned span = (unsigned)(hi - lo);

  // per-wave band window [dstart, dend), multiples of 8 steps
  const int dstart = (w == 0) ? 2 : (w == 1) ? 66 : (w == 2) ? 130 : 233;
  const int dend   = (w == 0) ? 282 : (w == 1) ? 386 : (w == 2) ? 450 : 513;
  const bool wlt3 = (w != 3);

  int cjb = dstart - t - 2;          // y index j-1 for step k=0 of the chunk
  int vdb = dstart - lo;             // d - lo for step k=0 of the chunk

  __syncthreads();                   // the ONLY block-wide barrier

  float lf = UBIG;                   // u[i][d-1] (own row, previous diagonal)
  float dgv;                         // u[i-1][d-2] = previous step's up
  if (w > 0) {
    const int need0 = dstart - 2;
    while (prog[w - 1] < need0) __builtin_amdgcn_s_sleep(1);
    __asm__ volatile("" ::: "memory");
    const float r0 = rngf[(w - 1) * 512 + dstart - 2];
    dgv = (lane == 0) ? r0 : UBIG;
  } else {
    dgv = (lane == 0) ? 0.0f : UBIG;   // r[0][0]=0 feeds cell (1,1) at d=2
  }

// data-only cost for step index IDX (y index (IDX)&255), u-scaled
#define COST(IDX) ({                                                     \
    const int cj_ = (IDX) & 255;                                         \
    const float a0 = x0 - ylds[cj_][0];                                  \
    const float a1 = x1 - ylds[cj_][1];                                  \
    const float a2 = x2 - ylds[cj_][2];                                  \
    const float dl1_ = fabsf(a0) + fabsf(a1) + fabsf(a2);                \
    const float om_  = 1.0f - E2(dl1_ * -1.44269504f);                   \
    om_ * om_ * dl1_ * -8.65617024f; })

  // first chunk's cost
  float cc[8], cn[8];
  #pragma unroll
  for (int k = 0; k < 8; ++k) cc[k] = COST(cjb + k);

  for (int dbase = dstart; dbase < dend; dbase += 8) {
    // ---- spin for producer, then fetch 8 boundary values ----
    float bb[8];
    if (w > 0) {
      const int need = dbase + 6;
      int pv = prog[w - 1];
      while (pv < need) { __builtin_amdgcn_s_sleep(1); pv = prog[w - 1]; }
      int gb = (w - 1) * 512 + dbase - 1;
      __asm__ volatile("" : "+v"(gb) : "v"(pv));   // fake dep: bb after spin
      #pragma unroll
      for (int k = 0; k < 8; ++k) bb[k] = rngf[gb + k];
    } else {
      #pragma unroll
      for (int k = 0; k < 8; ++k) bb[k] = UBIG;  // row 0: r[0][j>=1] = BIG
    }

    // ---- pure-register serial core: 8 softmin steps ----
    float rr[8];
    #pragma unroll
    for (int k = 0; k < 8; ++k) {
      // upv[lane] = lf[lane-1]; lane0 <- bb[k] via DPP 'old' operand
      const float upv = __int_as_float(__builtin_amdgcn_update_dpp(
          __float_as_int(bb[k]), __float_as_int(lf),
          0x138 /*wave_shr:1*/, 0xf, 0xf, false));

      const float mx = fmaxf(fmaxf(upv, lf), dgv);
      const float md = __builtin_amdgcn_fmed3f(upv, lf, dgv);
      const float mn = fminf(fminf(upv, lf), dgv);
      const float s  = 1.0f + E2(md - mx) + E2(mn - mx);
      float un = cc[k] + mx + LG2(s);
      un = ((unsigned)(vdb + k) <= span) ? un : UBIG;
      rr[k] = un;
      dgv = upv;
      lf = un;
    }

    // ---- prefetch NEXT chunk's cost (independent; fills core stall slots) ----
    #pragma unroll
    for (int k = 0; k < 8; ++k) cn[k] = COST(cjb + 8 + k);

    // ---- batched boundary publish ----
    if (wlt3 && lane == 63) {
      #pragma unroll
      for (int k = 0; k < 8; ++k) rngf[w * 512 + dbase + k] = rr[k];
    }
    __asm__ volatile("s_waitcnt lgkmcnt(0)" ::: "memory");
    if (wlt3 && lane == 0) prog[w] = dbase + 7;

    #pragma unroll
    for (int k = 0; k < 8; ++k) cc[k] = cn[k];
    cjb += 8;
    vdb += 8;
  }

  // release any lagging consumer reading past our window (values are UBIG-init)
  __asm__ volatile("s_waitcnt lgkmcnt(0)" ::: "memory");
  if (wlt3 && lane == 0) prog[w] = 0x7fffffff;

  // u[256][512] is lane 63 of wave 3's lf after its last step (d=512)
  if (t == 255) ws[blk] = lf * -0.0693147181f;
#undef COST
}

// Single block: reduce the 6 per-b arrays and emit (total, nag, kl, aux, trans_reg).
__global__ __launch_bounds__(128) void final_kernel(
    const float* __restrict__ ws, float* __restrict__ out) {
  const int t = threadIdx.x;   // 128 threads
  __shared__ float red[128];
  const int offs[6] = {0, 128, 256, 512, 640, 768};
  float sums[6];
  #pragma unroll
  for (int q = 0; q < 6; ++q) {
    red[t] = ws[offs[q] + t];
    __syncthreads();
    for (int s = 64; s > 0; s >>= 1) { if (t < s) red[t] += red[t + s]; __syncthreads(); }
    if (t == 0) sums[q] = red[0];
    __syncthreads();
  }
  if (t == 0) {
    const float inv = 1.0f / 128.0f;
    const float sim   = 2.0f * sums[0] * inv;   // sdtw(p,g)+sdtw(g,p) = 2x by symmetry
    const float dgen  = sums[1] * inv;
    const float dreal = sums[2] * inv;
    const float nag   = sim + fabsf(dgen - dreal);
    const float kl    = sums[3] * inv;
    const float aux   = sums[4] * inv;
    const float trans = sums[5] * inv;
    const float total = nag + 1.0f * kl + 0.1f * aux + 0.5f * trans;
    out[0] = total;
    out[1] = nag;
    out[2] = kl;
    out[3] = aux;
    out[4] = trans;
  }
}

extern "C" void kernel_launch(void* const* d_in, const int* in_sizes, int n_in,
                              void* d_out, int out_size, void* d_ws, size_t ws_size,
                              hipStream_t stream) {
  const float* pred = (const float*)d_in[0];   // (128,256,3)
  const float* gt   = (const float*)d_in[1];   // (128,256,3)
  const float* mu   = (const float*)d_in[2];   // (128,128)
  const float* lv   = (const float*)d_in[3];   // (128,128)
  const float* ptc  = (const float*)d_in[4];   // (128,1)
  const int*   pg   = (const int*)d_in[5];     // (128,)
  const int*   pr   = (const int*)d_in[6];     // (128,)
  float* ws  = (float*)d_ws;   // [0..383] sdtw, [512..639] kl, [640..767] aux, [768..895] trans
  float* out = (float*)d_out;  // 5 floats

  sdtw_kernel<<<512, 256, 0, stream>>>(pred, gt, mu, lv, ptc, pg, pr, ws);
  final_kernel<<<1, 128, 0, stream>>>(ws, out);
}